// Round 8
// baseline (348.681 us; speedup 1.0000x reference)
//
#include <hip/hip_runtime.h>

#define DD 128

typedef __attribute__((ext_vector_type(8))) short short8v;   // 8 bf16 = 4 VGPR
typedef __attribute__((ext_vector_type(4))) float float4v;   // MFMA acc

__device__ inline unsigned short f2b(float f) {              // fp32 -> bf16 RNE
    unsigned int x = __float_as_uint(f);
    return (unsigned short)((x + 0x7fffu + ((x >> 16) & 1u)) >> 16);
}
__device__ inline float blo(unsigned int u) { return __uint_as_float(u << 16); }
__device__ inline float bhi(unsigned int u) { return __uint_as_float(u & 0xffff0000u); }

// ---------------- conversions ----------------
__global__ void xconv_kernel(const float* __restrict__ x, unsigned short* __restrict__ xb,
                             int total4) {  // total4 = n*128/4
    for (int i = blockIdx.x * 256 + threadIdx.x; i < total4; i += gridDim.x * 256) {
        float4 v = ((const float4*)x)[i];
        unsigned int p0 = (unsigned int)f2b(v.x) | ((unsigned int)f2b(v.y) << 16);
        unsigned int p1 = (unsigned int)f2b(v.z) | ((unsigned int)f2b(v.w) << 16);
        ((uint2*)xb)[i] = make_uint2(p0, p1);
    }
}

// W[k][n] f32 -> Wt_hi[n][k], Wt_lo[n][k] bf16 (transposed, split precision)
__global__ void wconv_kernel(const float* __restrict__ W, unsigned short* __restrict__ WtHi,
                             unsigned short* __restrict__ WtLo) {
    int idx = blockIdx.x * 256 + threadIdx.x;  // k*128+n
    int k = idx >> 7, nn = idx & 127;
    float w = W[idx];
    unsigned short hi = f2b(w);
    float rem = w - __uint_as_float(((unsigned int)hi) << 16);
    WtHi[nn * 128 + k] = hi;
    WtLo[nn * 128 + k] = f2b(rem);
}

// ---------------- bucketed CSR build ----------------
__global__ void zero_nb_kernel(int* gcnt, int nb) {
    int t = threadIdx.x;
    if (t < nb) gcnt[t] = 0;
}

__global__ __launch_bounds__(256) void bucket_hist_kernel(const int* __restrict__ col,
                                                          int* gcnt, int E, int nb) {
    __shared__ int h[256];
    int t = threadIdx.x;
    h[t] = 0;
    __syncthreads();
    int base = blockIdx.x * 2048;
#pragma unroll
    for (int j = 0; j < 8; ++j) {
        int e = base + j * 256 + t;
        if (e < E) atomicAdd(&h[col[e] >> 8], 1);
    }
    __syncthreads();
    if (t < nb && h[t]) atomicAdd(&gcnt[t], h[t]);
}

__global__ void bucket_scan_kernel(const int* __restrict__ gcnt, int* __restrict__ bbase,
                                   int* __restrict__ bcur, int nb) {
    __shared__ int s[256];
    int t = threadIdx.x;
    int v = t < nb ? gcnt[t] : 0;
    s[t] = v;
    __syncthreads();
    for (int off = 1; off < 256; off <<= 1) {
        int add = t >= off ? s[t - off] : 0;
        __syncthreads();
        s[t] += add;
        __syncthreads();
    }
    if (t < nb) {
        bbase[t] = s[t] - v;
        bcur[t] = s[t] - v;
        if (t == nb - 1) bbase[nb] = s[t];
    }
}

// Bin edges into bucket regions. Record: x = f32(ew), y = (row<<8) | (col&255).
__global__ __launch_bounds__(256) void bin_kernel(const int* __restrict__ row,
                                                  const int* __restrict__ col,
                                                  const float* __restrict__ ew,
                                                  int* bcur, uint2* __restrict__ binned, int E) {
    __shared__ int h[256];
    __shared__ int resv[256];
    int t = threadIdx.x;
    h[t] = 0;
    __syncthreads();
    int base = blockIdx.x * 2048;
    int myb[8], myrank[8];
    uint2 myrec[8];
    bool val[8];
#pragma unroll
    for (int j = 0; j < 8; ++j) {
        int e = base + j * 256 + t;
        val[j] = e < E;
        if (val[j]) {
            int c = col[e], r = row[e];
            float w = ew[e];
            myb[j] = c >> 8;
            myrank[j] = atomicAdd(&h[myb[j]], 1);
            myrec[j] = make_uint2(__float_as_uint(w),
                                  ((unsigned int)r << 8) | (unsigned int)(c & 255));
        }
    }
    __syncthreads();
    if (h[t]) resv[t] = atomicAdd(&bcur[t], h[t]);
    __syncthreads();
#pragma unroll
    for (int j = 0; j < 8; ++j)
        if (val[j]) binned[resv[myb[j]] + myrank[j]] = myrec[j];
}

// Per-bucket: LDS histogram + fixed-point deg accumulation (order-independent).
__global__ __launch_bounds__(256) void pass2a_kernel(const uint2* __restrict__ binned,
                                                     const int* __restrict__ bbase,
                                                     int* __restrict__ count,
                                                     float* __restrict__ dinv, int n) {
    __shared__ unsigned int cnt[256];
    __shared__ unsigned int degf[256];
    int b = blockIdx.x, t = threadIdx.x;
    cnt[t] = 0; degf[t] = 0;
    __syncthreads();
    int s = bbase[b], e = bbase[b + 1];
    for (int k = s + t; k < e; k += 256) {
        uint2 rec = binned[k];
        int cl = rec.y & 255;
        atomicAdd(&cnt[cl], 1u);
        atomicAdd(&degf[cl], (unsigned int)__float2uint_rn(__uint_as_float(rec.x) * 16777216.0f));
    }
    __syncthreads();
    int node = b * 256 + t;
    if (node < n) {
        count[node] = (int)cnt[t];
        float deg = 1.0f + (float)((double)degf[t] * (1.0 / 16777216.0));
        dinv[node] = 1.0f / sqrtf(deg);
    }
}

// Per-bucket CSR placement into the bucket's contiguous window.
__global__ __launch_bounds__(256) void pass2b_kernel(const uint2* __restrict__ binned,
                                                     const int* __restrict__ bbase,
                                                     const int* __restrict__ startA,
                                                     const float* __restrict__ dinv,
                                                     unsigned int* __restrict__ sedge, int n) {
    __shared__ int cur[256];
    __shared__ float dv[256];
    int b = blockIdx.x, t = threadIdx.x;
    int node = b * 256 + t;
    cur[t] = node < n ? startA[node] : 0;
    dv[t] = node < n ? dinv[node] : 0.f;
    __syncthreads();
    int s = bbase[b], e = bbase[b + 1];
    for (int k = s + t; k < e; k += 256) {
        uint2 rec = binned[k];
        int cl = rec.y & 255;
        int r = (int)(rec.y >> 8);
        int pos = atomicAdd(&cur[cl], 1);
        float nv = dinv[r] * __uint_as_float(rec.x) * dv[cl];
        sedge[pos] = ((unsigned int)r << 16) | (unsigned int)f2b(nv);
    }
}

// ---------------- 3-stage parallel scan (over node counts) ----------------
__global__ void scan_partial_kernel(const int* __restrict__ count, int* __restrict__ blockSum,
                                    int n) {
    __shared__ int s[256];
    int i = blockIdx.x * 256 + threadIdx.x;
    s[threadIdx.x] = i < n ? count[i] : 0;
    __syncthreads();
    for (int off = 128; off > 0; off >>= 1) {
        if (threadIdx.x < off) s[threadIdx.x] += s[threadIdx.x + off];
        __syncthreads();
    }
    if (threadIdx.x == 0) blockSum[blockIdx.x] = s[0];
}

__global__ void scan_offsets_kernel(const int* __restrict__ blockSum, int* __restrict__ blockOff,
                                    int nb) {
    __shared__ int s[256];
    int t = threadIdx.x;
    int v = t < nb ? blockSum[t] : 0;
    s[t] = v;
    __syncthreads();
    for (int off = 1; off < 256; off <<= 1) {
        int add = t >= off ? s[t - off] : 0;
        __syncthreads();
        s[t] += add;
        __syncthreads();
    }
    if (t < nb) blockOff[t] = s[t] - v;
}

__global__ void scan_final_kernel(const int* __restrict__ count, const int* __restrict__ blockOff,
                                  int* __restrict__ start, int n) {
    __shared__ int s[256];
    int t = threadIdx.x;
    int i = blockIdx.x * 256 + t;
    int v = i < n ? count[i] : 0;
    s[t] = v;
    __syncthreads();
    for (int off = 1; off < 256; off <<= 1) {
        int add = t >= off ? s[t - off] : 0;
        __syncthreads();
        s[t] += add;
        __syncthreads();
    }
    int excl = s[t] - v + blockOff[blockIdx.x];
    if (i < n) {
        start[i] = excl;
        if (i == n - 1) start[n] = excl + v;
    }
}

// ---------------- MFMA GEMM: C_bf16[n x 128] = A_bf16[n x 128] @ (WtHi+WtLo)^T ----------------
__global__ __launch_bounds__(256) void mfma_gemm_kernel(const unsigned short* __restrict__ A,
                                                        const unsigned short* __restrict__ WtHi,
                                                        const unsigned short* __restrict__ WtLo,
                                                        unsigned short* __restrict__ C, int n) {
    __shared__ __align__(16) unsigned short WLh[16 * 128 * 8];  // 32 KB
    __shared__ __align__(16) unsigned short WLl[16 * 128 * 8];  // 32 KB
    const int tid = threadIdx.x;

    for (int c = tid; c < 2048; c += 256) {
        int nn = c >> 4, k8 = c & 15;
        short8v vh = *(const short8v*)(WtHi + nn * 128 + k8 * 8);
        short8v vl = *(const short8v*)(WtLo + nn * 128 + k8 * 8);
        *(short8v*)(WLh + (k8 * 128 + nn) * 8) = vh;
        *(short8v*)(WLl + (k8 * 128 + nn) * 8) = vl;
    }
    __syncthreads();

    const int lane = tid & 63;
    const int l15 = lane & 15, l4 = lane >> 4;
    const int m0 = blockIdx.x * 128 + (tid >> 6) * 32;

    float4v acc[2][8];
#pragma unroll
    for (int i = 0; i < 2; ++i)
#pragma unroll
        for (int j = 0; j < 8; ++j) acc[i][j] = (float4v){0.f, 0.f, 0.f, 0.f};

#pragma unroll
    for (int kb = 0; kb < 4; ++kb) {
        short8v aF[2];
#pragma unroll
        for (int i = 0; i < 2; ++i) {
            int r = m0 + i * 16 + l15;
            r = r < n ? r : n - 1;  // clamp; clamped rows never stored
            aF[i] = *(const short8v*)(A + (size_t)r * 128 + kb * 32 + l4 * 8);
        }
        const int k8 = kb * 4 + l4;
#pragma unroll
        for (int j = 0; j < 8; ++j) {
            short8v bh = *(const short8v*)(WLh + (k8 * 128 + j * 16 + l15) * 8);
            short8v bl = *(const short8v*)(WLl + (k8 * 128 + j * 16 + l15) * 8);
            acc[0][j] = __builtin_amdgcn_mfma_f32_16x16x32_bf16(aF[0], bh, acc[0][j], 0, 0, 0);
            acc[1][j] = __builtin_amdgcn_mfma_f32_16x16x32_bf16(aF[1], bh, acc[1][j], 0, 0, 0);
            acc[0][j] = __builtin_amdgcn_mfma_f32_16x16x32_bf16(aF[0], bl, acc[0][j], 0, 0, 0);
            acc[1][j] = __builtin_amdgcn_mfma_f32_16x16x32_bf16(aF[1], bl, acc[1][j], 0, 0, 0);
        }
    }

    // C/D layout (m89-verified): col = lane&15, row = (lane>>4)*4 + reg
#pragma unroll
    for (int i = 0; i < 2; ++i)
#pragma unroll
        for (int r = 0; r < 4; ++r) {
            int rr = m0 + i * 16 + l4 * 4 + r;
            if (rr < n) {
#pragma unroll
                for (int j = 0; j < 8; ++j)
                    C[(size_t)rr * 128 + j * 16 + l15] = f2b(acc[i][j][r]);
            }
        }
}

// ---------------- feature-tiled pull aggregation ----------------
// Pass q touches bytes [64q, 64q+64) of each 256B row -> exactly one 64B line per row,
// working set n*64B = 3.2MB < 4MB per-XCD L2. Wave = 1 node, 4 edge-slots x 16 lanes.
__global__ __launch_bounds__(256) void agg_q_kernel(const int* __restrict__ start,
                                                    const unsigned int* __restrict__ sedge,
                                                    const float* __restrict__ dinv,
                                                    const unsigned short* __restrict__ xw,
                                                    const float* __restrict__ bias,
                                                    unsigned short* __restrict__ h,
                                                    int n, int q) {
    const int i = blockIdx.x * 4 + (threadIdx.x >> 6);
    if (i >= n) return;
    const int lane = threadIdx.x & 63;
    const int sub = lane >> 4, f = lane & 15;  // edge-slot, dword index within line
    const unsigned int* xq = (const unsigned int*)xw + 16 * q + f;  // row stride 64 dwords

    float a0 = 0.f, a1 = 0.f;
    const int s = start[i], e = start[i + 1];
    int k = s + sub;
    for (; k + 4 < e; k += 8) {
        unsigned int peA = sedge[k], peB = sedge[k + 4];
        float nA = __uint_as_float((peA & 0xffffu) << 16);
        float nB = __uint_as_float((peB & 0xffffu) << 16);
        unsigned int uA = xq[(size_t)(peA >> 16) * 64];
        unsigned int uB = xq[(size_t)(peB >> 16) * 64];
        a0 += nA * blo(uA); a1 += nA * bhi(uA);
        a0 += nB * blo(uB); a1 += nB * bhi(uB);
    }
    if (k < e) {
        unsigned int pe = sedge[k];
        float nv = __uint_as_float((pe & 0xffffu) << 16);
        unsigned int u = xq[(size_t)(pe >> 16) * 64];
        a0 += nv * blo(u); a1 += nv * bhi(u);
    }
    // fold the 4 slots
    a0 += __shfl_xor(a0, 16); a0 += __shfl_xor(a0, 32);
    a1 += __shfl_xor(a1, 16); a1 += __shfl_xor(a1, 32);
    if (sub == 0) {
        float dv = dinv[i];
        unsigned int u = xq[(size_t)i * 64];
        a0 += dv * dv * blo(u);
        a1 += dv * dv * bhi(u);
        int fg = 32 * q + 2 * f;
        a0 = fmaxf(a0 + bias[fg], 0.f);
        a1 = fmaxf(a1 + bias[fg + 1], 0.f);
        ((unsigned int*)h)[(size_t)i * 64 + 16 * q + f] =
            (unsigned int)f2b(a0) | ((unsigned int)f2b(a1) << 16);
    }
}

// ---------------- readout ----------------
__global__ __launch_bounds__(64) void colsum_partial_kernel(const unsigned short* __restrict__ h,
                                                            float* __restrict__ partial, int n) {
    int t = threadIdx.x;
    float a0 = 0.f, a1 = 0.f;
    for (int r = blockIdx.x; r < n; r += gridDim.x) {
        unsigned int u = *(const unsigned int*)(h + (size_t)r * DD + 2 * t);
        a0 += blo(u); a1 += bhi(u);
    }
    partial[blockIdx.x * DD + 2 * t] = a0;
    partial[blockIdx.x * DD + 2 * t + 1] = a1;
}

__global__ void final_kernel(const float* __restrict__ partial, const float* __restrict__ Wm,
                             const float* __restrict__ bm, float* __restrict__ out, int n) {
    __shared__ float g[DD];
    int t = threadIdx.x;
    float acc = 0.f;
    for (int b = 0; b < 512; ++b) acc += partial[b * DD + t];
    g[t] = acc / (float)n;
    __syncthreads();
    if (t < 10) {
        float o = bm[t];
#pragma unroll
        for (int d = 0; d < DD; ++d) o += g[d] * Wm[d * 10 + t];
        out[t] = o;
    }
}

extern "C" void kernel_launch(void* const* d_in, const int* in_sizes, int n_in,
                              void* d_out, int out_size, void* d_ws, size_t ws_size,
                              hipStream_t stream) {
    const float* x  = (const float*)d_in[0];
    const int*   ei = (const int*)d_in[1];
    const float* ew = (const float*)d_in[2];
    const float* W1 = (const float*)d_in[3];
    const float* b1 = (const float*)d_in[4];
    const float* W2 = (const float*)d_in[5];
    const float* b2 = (const float*)d_in[6];
    const float* Wm = (const float*)d_in[7];
    const float* bm = (const float*)d_in[8];
    float* out = (float*)d_out;

    const int n = in_sizes[0] / DD;   // 50000
    const int E = in_sizes[2];        // 800000
    const int* row = ei;
    const int* col = ei + E;

    const int nb = (n + 255) >> 8;            // 196 buckets (n <= 65536)
    const int nodeBlocks = (n + 255) / 256;   // 196
    const int edgeChunks = (E + 2047) / 2048; // 391

    uint2* binned = (uint2*)d_ws;                            // E (8B records)
    unsigned int* sedge = (unsigned int*)(binned + E);       // E (4B records)
    float* dinv    = (float*)(sedge + E);                    // n
    int*   count   = (int*)(dinv + n);                       // n
    int*   startA  = count + n;                              // n+1
    float* partial = (float*)(startA + n + 1);               // 512*128
    int*   blockSum = (int*)(partial + 512 * DD);            // nodeBlocks
    int*   blockOff = blockSum + nodeBlocks;                 // nodeBlocks
    int*   gcnt    = blockOff + nodeBlocks;                  // nb
    int*   bbase   = gcnt + nb;                              // nb+1
    int*   bcur    = bbase + nb + 1;                         // nb
    uintptr_t p = (uintptr_t)(bcur + nb);
    p = (p + 15) & ~(uintptr_t)15;
    unsigned short* xb   = (unsigned short*)p;               // n*128 bf16 row-major
    unsigned short* T0   = xb + (size_t)n * DD;
    unsigned short* T1   = T0 + (size_t)n * DD;
    unsigned short* Wt1h = T1 + (size_t)n * DD;              // 16384 each
    unsigned short* Wt1l = Wt1h + 16384;
    unsigned short* Wt2h = Wt1l + 16384;
    unsigned short* Wt2l = Wt2h + 16384;

    // --- conversions ---
    xconv_kernel<<<1024, 256, 0, stream>>>(x, xb, n * DD / 4);
    wconv_kernel<<<64, 256, 0, stream>>>(W1, Wt1h, Wt1l);
    wconv_kernel<<<64, 256, 0, stream>>>(W2, Wt2h, Wt2l);

    // --- bucketed CSR build ---
    zero_nb_kernel<<<1, 256, 0, stream>>>(gcnt, nb);
    bucket_hist_kernel<<<edgeChunks, 256, 0, stream>>>(col, gcnt, E, nb);
    bucket_scan_kernel<<<1, 256, 0, stream>>>(gcnt, bbase, bcur, nb);
    bin_kernel<<<edgeChunks, 256, 0, stream>>>(row, col, ew, bcur, binned, E);
    pass2a_kernel<<<nb, 256, 0, stream>>>(binned, bbase, count, dinv, n);
    scan_partial_kernel<<<nodeBlocks, 256, 0, stream>>>(count, blockSum, n);
    scan_offsets_kernel<<<1, 256, 0, stream>>>(blockSum, blockOff, nodeBlocks);
    scan_final_kernel<<<nodeBlocks, 256, 0, stream>>>(count, blockOff, startA, n);
    pass2b_kernel<<<nb, 256, 0, stream>>>(binned, bbase, startA, dinv, sedge, n);

    const int gemmBlocks = (n + 127) / 128;  // 391
    const int aggBlocks = (n + 3) / 4;       // 12500

    // --- layer 1 ---
    mfma_gemm_kernel<<<gemmBlocks, 256, 0, stream>>>(xb, Wt1h, Wt1l, T0, n);
    for (int q = 0; q < 4; ++q)
        agg_q_kernel<<<aggBlocks, 256, 0, stream>>>(startA, sedge, dinv, T0, b1, T1, n, q);

    // --- layer 2 ---
    mfma_gemm_kernel<<<gemmBlocks, 256, 0, stream>>>(T1, Wt2h, Wt2l, T0, n);
    for (int q = 0; q < 4; ++q)
        agg_q_kernel<<<aggBlocks, 256, 0, stream>>>(startA, sedge, dinv, T0, b2, T1, n, q);

    // --- readout ---
    colsum_partial_kernel<<<512, 64, 0, stream>>>(T1, partial, n);
    final_kernel<<<1, 128, 0, stream>>>(partial, Wm, bm, out, n);
}

// Round 9
// 209.515 us; speedup vs baseline: 1.6642x; 1.6642x over previous
//
#include <hip/hip_runtime.h>

#define DD 128

typedef __attribute__((ext_vector_type(8))) short short8v;   // 8 bf16 = 4 VGPR
typedef __attribute__((ext_vector_type(4))) float float4v;   // MFMA acc

__device__ inline unsigned short f2b(float f) {              // fp32 -> bf16 RNE
    unsigned int x = __float_as_uint(f);
    return (unsigned short)((x + 0x7fffu + ((x >> 16) & 1u)) >> 16);
}
__device__ inline float blo(unsigned int u) { return __uint_as_float(u << 16); }
__device__ inline float bhi(unsigned int u) { return __uint_as_float(u & 0xffff0000u); }

// ---------------- conversions ----------------
__global__ void xconv_kernel(const float* __restrict__ x, unsigned short* __restrict__ xb,
                             int total4) {  // total4 = n*128/4
    for (int i = blockIdx.x * 256 + threadIdx.x; i < total4; i += gridDim.x * 256) {
        float4 v = ((const float4*)x)[i];
        unsigned int p0 = (unsigned int)f2b(v.x) | ((unsigned int)f2b(v.y) << 16);
        unsigned int p1 = (unsigned int)f2b(v.z) | ((unsigned int)f2b(v.w) << 16);
        ((uint2*)xb)[i] = make_uint2(p0, p1);
    }
}

// Both W1,W2 -> transposed split-precision bf16; block 0 also zeroes gcnt.
__global__ void wconv2_kernel(const float* __restrict__ W1, unsigned short* __restrict__ Wt1h,
                              unsigned short* __restrict__ Wt1l,
                              const float* __restrict__ W2, unsigned short* __restrict__ Wt2h,
                              unsigned short* __restrict__ Wt2l,
                              int* gcnt, int nb) {
    int t = threadIdx.x;
    if (blockIdx.x == 0 && t < nb) gcnt[t] = 0;
    int which = blockIdx.x >> 6;                 // 0: W1, 1: W2
    int idx = (blockIdx.x & 63) * 256 + t;       // k*128+n
    int k = idx >> 7, nn = idx & 127;
    const float* W = which ? W2 : W1;
    unsigned short* Hh = which ? Wt2h : Wt1h;
    unsigned short* Hl = which ? Wt2l : Wt1l;
    float w = W[idx];
    unsigned short hi = f2b(w);
    float rem = w - __uint_as_float(((unsigned int)hi) << 16);
    Hh[nn * 128 + k] = hi;
    Hl[nn * 128 + k] = f2b(rem);
}

// ---------------- bucketed CSR build ----------------
__global__ __launch_bounds__(256) void bucket_hist_kernel(const int* __restrict__ col,
                                                          int* gcnt, int E, int nb) {
    __shared__ int h[256];
    int t = threadIdx.x;
    h[t] = 0;
    __syncthreads();
    int base = blockIdx.x * 2048;
#pragma unroll
    for (int j = 0; j < 8; ++j) {
        int e = base + j * 256 + t;
        if (e < E) atomicAdd(&h[col[e] >> 8], 1);
    }
    __syncthreads();
    if (t < nb && h[t]) atomicAdd(&gcnt[t], h[t]);
}

__global__ void bucket_scan_kernel(const int* __restrict__ gcnt, int* __restrict__ bbase,
                                   int* __restrict__ bcur, int nb) {
    __shared__ int s[256];
    int t = threadIdx.x;
    int v = t < nb ? gcnt[t] : 0;
    s[t] = v;
    __syncthreads();
    for (int off = 1; off < 256; off <<= 1) {
        int add = t >= off ? s[t - off] : 0;
        __syncthreads();
        s[t] += add;
        __syncthreads();
    }
    if (t < nb) {
        bbase[t] = s[t] - v;
        bcur[t] = s[t] - v;
        if (t == nb - 1) bbase[nb] = s[t];
    }
}

// Bin edges into bucket regions. Record: x = f32(ew), y = (row<<8) | (col&255).
__global__ __launch_bounds__(256) void bin_kernel(const int* __restrict__ row,
                                                  const int* __restrict__ col,
                                                  const float* __restrict__ ew,
                                                  int* bcur, uint2* __restrict__ binned, int E) {
    __shared__ int h[256];
    __shared__ int resv[256];
    int t = threadIdx.x;
    h[t] = 0;
    __syncthreads();
    int base = blockIdx.x * 2048;
    int myb[8], myrank[8];
    uint2 myrec[8];
    bool val[8];
#pragma unroll
    for (int j = 0; j < 8; ++j) {
        int e = base + j * 256 + t;
        val[j] = e < E;
        if (val[j]) {
            int c = col[e], r = row[e];
            float w = ew[e];
            myb[j] = c >> 8;
            myrank[j] = atomicAdd(&h[myb[j]], 1);
            myrec[j] = make_uint2(__float_as_uint(w),
                                  ((unsigned int)r << 8) | (unsigned int)(c & 255));
        }
    }
    __syncthreads();
    if (h[t]) resv[t] = atomicAdd(&bcur[t], h[t]);
    __syncthreads();
#pragma unroll
    for (int j = 0; j < 8; ++j)
        if (val[j]) binned[resv[myb[j]] + myrank[j]] = myrec[j];
}

// Per-bucket: LDS histogram + fixed-point deg accumulation + INTRA-BUCKET SCAN -> startA.
// Bucket b owns nodes [256b, 256b+256); their CSR window is [bbase[b], bbase[b+1]).
__global__ __launch_bounds__(256) void pass2a_kernel(const uint2* __restrict__ binned,
                                                     const int* __restrict__ bbase,
                                                     int* __restrict__ startA,
                                                     float* __restrict__ dinv, int n) {
    __shared__ unsigned int cnt[256];
    __shared__ unsigned int degf[256];
    __shared__ int sc[256];
    int b = blockIdx.x, t = threadIdx.x;
    cnt[t] = 0; degf[t] = 0;
    __syncthreads();
    int s = bbase[b], e = bbase[b + 1];
    for (int k = s + t; k < e; k += 256) {
        uint2 rec = binned[k];
        int cl = rec.y & 255;
        atomicAdd(&cnt[cl], 1u);
        atomicAdd(&degf[cl], (unsigned int)__float2uint_rn(__uint_as_float(rec.x) * 16777216.0f));
    }
    __syncthreads();
    int v = (int)cnt[t];
    sc[t] = v;
    __syncthreads();
    for (int off = 1; off < 256; off <<= 1) {
        int add = t >= off ? sc[t - off] : 0;
        __syncthreads();
        sc[t] += add;
        __syncthreads();
    }
    int node = b * 256 + t;
    if (node < n) {
        startA[node] = s + sc[t] - v;  // exclusive
        if (node == n - 1) startA[n] = s + sc[t];
        float deg = 1.0f + (float)((double)degf[t] * (1.0 / 16777216.0));
        dinv[node] = 1.0f / sqrtf(deg);
    }
}

// Per-bucket CSR placement into the bucket's contiguous window.
__global__ __launch_bounds__(256) void pass2b_kernel(const uint2* __restrict__ binned,
                                                     const int* __restrict__ bbase,
                                                     const int* __restrict__ startA,
                                                     const float* __restrict__ dinv,
                                                     unsigned int* __restrict__ sedge, int n) {
    __shared__ int cur[256];
    __shared__ float dv[256];
    int b = blockIdx.x, t = threadIdx.x;
    int node = b * 256 + t;
    cur[t] = node < n ? startA[node] : 0;
    dv[t] = node < n ? dinv[node] : 0.f;
    __syncthreads();
    int s = bbase[b], e = bbase[b + 1];
    for (int k = s + t; k < e; k += 256) {
        uint2 rec = binned[k];
        int cl = rec.y & 255;
        int r = (int)(rec.y >> 8);
        int pos = atomicAdd(&cur[cl], 1);
        float nv = dinv[r] * __uint_as_float(rec.x) * dv[cl];
        sedge[pos] = ((unsigned int)r << 16) | (unsigned int)f2b(nv);
    }
}

// ---------------- MFMA GEMM: C_bf16[n x 128] = A_bf16[n x 128] @ (WtHi+WtLo)^T ----------------
__global__ __launch_bounds__(256) void mfma_gemm_kernel(const unsigned short* __restrict__ A,
                                                        const unsigned short* __restrict__ WtHi,
                                                        const unsigned short* __restrict__ WtLo,
                                                        unsigned short* __restrict__ C, int n) {
    __shared__ __align__(16) unsigned short WLh[16 * 128 * 8];  // 32 KB
    __shared__ __align__(16) unsigned short WLl[16 * 128 * 8];  // 32 KB
    const int tid = threadIdx.x;

    for (int c = tid; c < 2048; c += 256) {
        int nn = c >> 4, k8 = c & 15;
        short8v vh = *(const short8v*)(WtHi + nn * 128 + k8 * 8);
        short8v vl = *(const short8v*)(WtLo + nn * 128 + k8 * 8);
        *(short8v*)(WLh + (k8 * 128 + nn) * 8) = vh;
        *(short8v*)(WLl + (k8 * 128 + nn) * 8) = vl;
    }
    __syncthreads();

    const int lane = tid & 63;
    const int l15 = lane & 15, l4 = lane >> 4;
    const int m0 = blockIdx.x * 128 + (tid >> 6) * 32;

    float4v acc[2][8];
#pragma unroll
    for (int i = 0; i < 2; ++i)
#pragma unroll
        for (int j = 0; j < 8; ++j) acc[i][j] = (float4v){0.f, 0.f, 0.f, 0.f};

#pragma unroll
    for (int kb = 0; kb < 4; ++kb) {
        short8v aF[2];
#pragma unroll
        for (int i = 0; i < 2; ++i) {
            int r = m0 + i * 16 + l15;
            r = r < n ? r : n - 1;  // clamp; clamped rows never stored
            aF[i] = *(const short8v*)(A + (size_t)r * 128 + kb * 32 + l4 * 8);
        }
        const int k8 = kb * 4 + l4;
#pragma unroll
        for (int j = 0; j < 8; ++j) {
            short8v bh = *(const short8v*)(WLh + (k8 * 128 + j * 16 + l15) * 8);
            short8v bl = *(const short8v*)(WLl + (k8 * 128 + j * 16 + l15) * 8);
            acc[0][j] = __builtin_amdgcn_mfma_f32_16x16x32_bf16(aF[0], bh, acc[0][j], 0, 0, 0);
            acc[1][j] = __builtin_amdgcn_mfma_f32_16x16x32_bf16(aF[1], bh, acc[1][j], 0, 0, 0);
            acc[0][j] = __builtin_amdgcn_mfma_f32_16x16x32_bf16(aF[0], bl, acc[0][j], 0, 0, 0);
            acc[1][j] = __builtin_amdgcn_mfma_f32_16x16x32_bf16(aF[1], bl, acc[1][j], 0, 0, 0);
        }
    }

    // C/D layout (m89-verified): col = lane&15, row = (lane>>4)*4 + reg
#pragma unroll
    for (int i = 0; i < 2; ++i)
#pragma unroll
        for (int r = 0; r < 4; ++r) {
            int rr = m0 + i * 16 + l4 * 4 + r;
            if (rr < n) {
#pragma unroll
                for (int j = 0; j < 8; ++j)
                    C[(size_t)rr * 128 + j * 16 + l15] = f2b(acc[i][j][r]);
            }
        }
}

// ---------------- pull aggregation: 4 nodes / 256-thr block, 16-deep unroll, no atomics ----------------
__global__ __launch_bounds__(256) void agg_kernel(const int* __restrict__ start,
                                                  const unsigned int* __restrict__ sedge,
                                                  const float* __restrict__ dinv,
                                                  const unsigned short* __restrict__ xw,
                                                  const float* __restrict__ bias,
                                                  unsigned short* __restrict__ h, int n) {
    const int i = blockIdx.x * 4 + (threadIdx.x >> 6);
    if (i >= n) return;
    const int t = threadIdx.x & 63;  // feature pair (2t, 2t+1)
    const float dv = dinv[i];
    unsigned int u = *(const unsigned int*)(xw + (size_t)i * DD + 2 * t);
    float a0 = dv * dv * blo(u);
    float a1 = dv * dv * bhi(u);
    const int s = start[i], e = start[i + 1];
    int k = s;
    for (; k + 15 < e; k += 16) {
        unsigned int pe[16], uu[16];
        float nv[16];
#pragma unroll
        for (int j = 0; j < 16; ++j) pe[j] = sedge[k + j];
#pragma unroll
        for (int j = 0; j < 16; ++j) {
            nv[j] = __uint_as_float((pe[j] & 0xffffu) << 16);
            uu[j] = *(const unsigned int*)(xw + (size_t)(pe[j] >> 16) * DD + 2 * t);
        }
#pragma unroll
        for (int j = 0; j < 16; ++j) {
            a0 += nv[j] * blo(uu[j]);
            a1 += nv[j] * bhi(uu[j]);
        }
    }
    for (; k + 3 < e; k += 4) {
        unsigned int pe[4], uu[4];
        float nv[4];
#pragma unroll
        for (int j = 0; j < 4; ++j) pe[j] = sedge[k + j];
#pragma unroll
        for (int j = 0; j < 4; ++j) {
            nv[j] = __uint_as_float((pe[j] & 0xffffu) << 16);
            uu[j] = *(const unsigned int*)(xw + (size_t)(pe[j] >> 16) * DD + 2 * t);
        }
#pragma unroll
        for (int j = 0; j < 4; ++j) {
            a0 += nv[j] * blo(uu[j]);
            a1 += nv[j] * bhi(uu[j]);
        }
    }
    for (; k < e; ++k) {
        unsigned int pe = sedge[k];
        float nvv = __uint_as_float((pe & 0xffffu) << 16);
        unsigned int u2 = *(const unsigned int*)(xw + (size_t)(pe >> 16) * DD + 2 * t);
        a0 += nvv * blo(u2);
        a1 += nvv * bhi(u2);
    }
    a0 = fmaxf(a0 + bias[2 * t], 0.f);
    a1 = fmaxf(a1 + bias[2 * t + 1], 0.f);
    *(unsigned int*)(h + (size_t)i * DD + 2 * t) =
        (unsigned int)f2b(a0) | ((unsigned int)f2b(a1) << 16);
}

// ---------------- readout ----------------
__global__ __launch_bounds__(64) void colsum_partial_kernel(const unsigned short* __restrict__ h,
                                                            float* __restrict__ partial, int n) {
    int t = threadIdx.x;
    float a0 = 0.f, a1 = 0.f;
    for (int r = blockIdx.x; r < n; r += gridDim.x) {
        unsigned int u = *(const unsigned int*)(h + (size_t)r * DD + 2 * t);
        a0 += blo(u); a1 += bhi(u);
    }
    partial[blockIdx.x * DD + 2 * t] = a0;
    partial[blockIdx.x * DD + 2 * t + 1] = a1;
}

__global__ void final_kernel(const float* __restrict__ partial, const float* __restrict__ Wm,
                             const float* __restrict__ bm, float* __restrict__ out, int n) {
    __shared__ float g[DD];
    int t = threadIdx.x;
    float acc = 0.f;
    for (int b = 0; b < 512; ++b) acc += partial[b * DD + t];
    g[t] = acc / (float)n;
    __syncthreads();
    if (t < 10) {
        float o = bm[t];
#pragma unroll
        for (int d = 0; d < DD; ++d) o += g[d] * Wm[d * 10 + t];
        out[t] = o;
    }
}

extern "C" void kernel_launch(void* const* d_in, const int* in_sizes, int n_in,
                              void* d_out, int out_size, void* d_ws, size_t ws_size,
                              hipStream_t stream) {
    const float* x  = (const float*)d_in[0];
    const int*   ei = (const int*)d_in[1];
    const float* ew = (const float*)d_in[2];
    const float* W1 = (const float*)d_in[3];
    const float* b1 = (const float*)d_in[4];
    const float* W2 = (const float*)d_in[5];
    const float* b2 = (const float*)d_in[6];
    const float* Wm = (const float*)d_in[7];
    const float* bm = (const float*)d_in[8];
    float* out = (float*)d_out;

    const int n = in_sizes[0] / DD;   // 50000
    const int E = in_sizes[2];        // 800000
    const int* row = ei;
    const int* col = ei + E;

    const int nb = (n + 255) >> 8;            // 196 buckets (n <= 65536)
    const int edgeChunks = (E + 2047) / 2048; // 391

    uint2* binned = (uint2*)d_ws;                            // E (8B records)
    unsigned int* sedge = (unsigned int*)(binned + E);       // E (4B records)
    float* dinv    = (float*)(sedge + E);                    // n
    int*   startA  = (int*)(dinv + n);                       // n+1
    float* partial = (float*)(startA + n + 1);               // 512*128
    int*   gcnt    = (int*)(partial + 512 * DD);             // nb
    int*   bbase   = gcnt + nb;                              // nb+1
    int*   bcur    = bbase + nb + 1;                         // nb
    uintptr_t p = (uintptr_t)(bcur + nb);
    p = (p + 15) & ~(uintptr_t)15;
    unsigned short* xb   = (unsigned short*)p;               // n*128 bf16 row-major
    unsigned short* T0   = xb + (size_t)n * DD;
    unsigned short* T1   = T0 + (size_t)n * DD;
    unsigned short* Wt1h = T1 + (size_t)n * DD;              // 16384 each
    unsigned short* Wt1l = Wt1h + 16384;
    unsigned short* Wt2h = Wt1l + 16384;
    unsigned short* Wt2l = Wt2h + 16384;

    // --- conversions (+ gcnt zero inside wconv2 block 0) ---
    xconv_kernel<<<1024, 256, 0, stream>>>(x, xb, n * DD / 4);
    wconv2_kernel<<<128, 256, 0, stream>>>(W1, Wt1h, Wt1l, W2, Wt2h, Wt2l, gcnt, nb);

    // --- bucketed CSR build (node scan fused into pass2a) ---
    bucket_hist_kernel<<<edgeChunks, 256, 0, stream>>>(col, gcnt, E, nb);
    bucket_scan_kernel<<<1, 256, 0, stream>>>(gcnt, bbase, bcur, nb);
    bin_kernel<<<edgeChunks, 256, 0, stream>>>(row, col, ew, bcur, binned, E);
    pass2a_kernel<<<nb, 256, 0, stream>>>(binned, bbase, startA, dinv, n);
    pass2b_kernel<<<nb, 256, 0, stream>>>(binned, bbase, startA, dinv, sedge, n);

    const int gemmBlocks = (n + 127) / 128;  // 391
    const int aggBlocks = (n + 3) / 4;       // 12500

    // --- layer 1 ---
    mfma_gemm_kernel<<<gemmBlocks, 256, 0, stream>>>(xb, Wt1h, Wt1l, T0, n);
    agg_kernel<<<aggBlocks, 256, 0, stream>>>(startA, sedge, dinv, T0, b1, T1, n);

    // --- layer 2 ---
    mfma_gemm_kernel<<<gemmBlocks, 256, 0, stream>>>(T1, Wt2h, Wt2l, T0, n);
    agg_kernel<<<aggBlocks, 256, 0, stream>>>(startA, sedge, dinv, T0, b2, T1, n);

    // --- readout ---
    colsum_partial_kernel<<<512, 64, 0, stream>>>(T1, partial, n);
    final_kernel<<<1, 128, 0, stream>>>(partial, Wm, bm, out, n);
}

// Round 10
// 205.571 us; speedup vs baseline: 1.6962x; 1.0192x over previous
//
#include <hip/hip_runtime.h>

#define DD 128

typedef __attribute__((ext_vector_type(8))) short short8v;   // 8 bf16 = 4 VGPR
typedef __attribute__((ext_vector_type(4))) float float4v;   // MFMA acc

__device__ inline unsigned short f2b(float f) {              // fp32 -> bf16 RNE
    unsigned int x = __float_as_uint(f);
    return (unsigned short)((x + 0x7fffu + ((x >> 16) & 1u)) >> 16);
}
__device__ inline float blo(unsigned int u) { return __uint_as_float(u << 16); }
__device__ inline float bhi(unsigned int u) { return __uint_as_float(u & 0xffff0000u); }

// Both W1,W2 -> transposed split-precision bf16; block 0 also zeroes gcnt.
__global__ void wconv2_kernel(const float* __restrict__ W1, unsigned short* __restrict__ Wt1h,
                              unsigned short* __restrict__ Wt1l,
                              const float* __restrict__ W2, unsigned short* __restrict__ Wt2h,
                              unsigned short* __restrict__ Wt2l,
                              int* gcnt, int nb) {
    int t = threadIdx.x;
    if (blockIdx.x == 0 && t < nb) gcnt[t] = 0;
    int which = blockIdx.x >> 6;                 // 0: W1, 1: W2
    int idx = (blockIdx.x & 63) * 256 + t;       // k*128+n
    int k = idx >> 7, nn = idx & 127;
    const float* W = which ? W2 : W1;
    unsigned short* Hh = which ? Wt2h : Wt1h;
    unsigned short* Hl = which ? Wt2l : Wt1l;
    float w = W[idx];
    unsigned short hi = f2b(w);
    float rem = w - __uint_as_float(((unsigned int)hi) << 16);
    Hh[nn * 128 + k] = hi;
    Hl[nn * 128 + k] = f2b(rem);
}

// ---------------- bucketed CSR build ----------------
__global__ __launch_bounds__(256) void bucket_hist_kernel(const int* __restrict__ col,
                                                          int* gcnt, int E, int nb) {
    __shared__ int h[256];
    int t = threadIdx.x;
    h[t] = 0;
    __syncthreads();
    int base = blockIdx.x * 2048;
#pragma unroll
    for (int j = 0; j < 8; ++j) {
        int e = base + j * 256 + t;
        if (e < E) atomicAdd(&h[col[e] >> 8], 1);
    }
    __syncthreads();
    if (t < nb && h[t]) atomicAdd(&gcnt[t], h[t]);
}

__global__ void bucket_scan_kernel(const int* __restrict__ gcnt, int* __restrict__ bbase,
                                   int* __restrict__ bcur, int nb) {
    __shared__ int s[256];
    int t = threadIdx.x;
    int v = t < nb ? gcnt[t] : 0;
    s[t] = v;
    __syncthreads();
    for (int off = 1; off < 256; off <<= 1) {
        int add = t >= off ? s[t - off] : 0;
        __syncthreads();
        s[t] += add;
        __syncthreads();
    }
    if (t < nb) {
        bbase[t] = s[t] - v;
        bcur[t] = s[t] - v;
        if (t == nb - 1) bbase[nb] = s[t];
    }
}

// Bin edges into bucket regions. Record: x = f32(ew), y = (row<<8) | (col&255).
__global__ __launch_bounds__(256) void bin_kernel(const int* __restrict__ row,
                                                  const int* __restrict__ col,
                                                  const float* __restrict__ ew,
                                                  int* bcur, uint2* __restrict__ binned, int E) {
    __shared__ int h[256];
    __shared__ int resv[256];
    int t = threadIdx.x;
    h[t] = 0;
    __syncthreads();
    int base = blockIdx.x * 2048;
    int myb[8], myrank[8];
    uint2 myrec[8];
    bool val[8];
#pragma unroll
    for (int j = 0; j < 8; ++j) {
        int e = base + j * 256 + t;
        val[j] = e < E;
        if (val[j]) {
            int c = col[e], r = row[e];
            float w = ew[e];
            myb[j] = c >> 8;
            myrank[j] = atomicAdd(&h[myb[j]], 1);
            myrec[j] = make_uint2(__float_as_uint(w),
                                  ((unsigned int)r << 8) | (unsigned int)(c & 255));
        }
    }
    __syncthreads();
    if (h[t]) resv[t] = atomicAdd(&bcur[t], h[t]);
    __syncthreads();
#pragma unroll
    for (int j = 0; j < 8; ++j)
        if (val[j]) binned[resv[myb[j]] + myrank[j]] = myrec[j];
}

// Merged pass2a+pass2b: per-bucket count + fixed-point deg + intra-bucket scan -> startA/dinv,
// then CSR placement (second sweep is L2-hot). Record no longer needs dinv:
// sedge = (row<<16) | bf16(ew)  [dinv folded into GEMM epilogue + agg final scale].
__global__ __launch_bounds__(256) void build_csr_kernel(const uint2* __restrict__ binned,
                                                        const int* __restrict__ bbase,
                                                        int* __restrict__ startA,
                                                        float* __restrict__ dinv,
                                                        unsigned int* __restrict__ sedge, int n) {
    __shared__ unsigned int cnt[256];
    __shared__ unsigned int degf[256];
    __shared__ int sc[256];
    __shared__ int cur[256];
    int b = blockIdx.x, t = threadIdx.x;
    cnt[t] = 0; degf[t] = 0;
    __syncthreads();
    int s = bbase[b], e = bbase[b + 1];
    for (int k = s + t; k < e; k += 256) {
        uint2 rec = binned[k];
        int cl = rec.y & 255;
        atomicAdd(&cnt[cl], 1u);
        atomicAdd(&degf[cl], (unsigned int)__float2uint_rn(__uint_as_float(rec.x) * 16777216.0f));
    }
    __syncthreads();
    int v = (int)cnt[t];
    sc[t] = v;
    __syncthreads();
    for (int off = 1; off < 256; off <<= 1) {
        int add = t >= off ? sc[t - off] : 0;
        __syncthreads();
        sc[t] += add;
        __syncthreads();
    }
    int myStart = s + sc[t] - v;  // exclusive
    cur[t] = myStart;
    int node = b * 256 + t;
    if (node < n) {
        startA[node] = myStart;
        if (node == n - 1) startA[n] = s + sc[t];
        float deg = 1.0f + (float)((double)degf[t] * (1.0 / 16777216.0));
        dinv[node] = 1.0f / sqrtf(deg);
    }
    __syncthreads();
    for (int k = s + t; k < e; k += 256) {
        uint2 rec = binned[k];
        int cl = rec.y & 255;
        int r = (int)(rec.y >> 8);
        int pos = atomicAdd(&cur[cl], 1);
        sedge[pos] = ((unsigned int)r << 16) | (unsigned int)f2b(__uint_as_float(rec.x));
    }
}

// ---------------- MFMA GEMM: Ts_bf16[r] = dinv[r] * (A[r] @ (WtHi+WtLo)^T) ----------------
// F32A=true: A is fp32 (layer-1 input x, converted in-register) -> xconv pass eliminated.
template <bool F32A>
__global__ __launch_bounds__(256) void mfma_gemm_kernel(const void* __restrict__ Av,
                                                        const unsigned short* __restrict__ WtHi,
                                                        const unsigned short* __restrict__ WtLo,
                                                        const float* __restrict__ dinv,
                                                        unsigned short* __restrict__ C, int n) {
    __shared__ __align__(16) unsigned short WLh[16 * 128 * 8];  // 32 KB
    __shared__ __align__(16) unsigned short WLl[16 * 128 * 8];  // 32 KB
    const int tid = threadIdx.x;

    for (int c = tid; c < 2048; c += 256) {
        int nn = c >> 4, k8 = c & 15;
        short8v vh = *(const short8v*)(WtHi + nn * 128 + k8 * 8);
        short8v vl = *(const short8v*)(WtLo + nn * 128 + k8 * 8);
        *(short8v*)(WLh + (k8 * 128 + nn) * 8) = vh;
        *(short8v*)(WLl + (k8 * 128 + nn) * 8) = vl;
    }
    __syncthreads();

    const int lane = tid & 63;
    const int l15 = lane & 15, l4 = lane >> 4;
    const int m0 = blockIdx.x * 128 + (tid >> 6) * 32;

    float4v acc[2][8];
#pragma unroll
    for (int i = 0; i < 2; ++i)
#pragma unroll
        for (int j = 0; j < 8; ++j) acc[i][j] = (float4v){0.f, 0.f, 0.f, 0.f};

#pragma unroll
    for (int kb = 0; kb < 4; ++kb) {
        short8v aF[2];
#pragma unroll
        for (int i = 0; i < 2; ++i) {
            int r = m0 + i * 16 + l15;
            r = r < n ? r : n - 1;  // clamp; clamped rows never stored
            if constexpr (F32A) {
                const float* xr = (const float*)Av + (size_t)r * 128 + kb * 32 + l4 * 8;
                float4 v0 = ((const float4*)xr)[0];
                float4 v1 = ((const float4*)xr)[1];
                short8v a;
                a[0] = (short)f2b(v0.x); a[1] = (short)f2b(v0.y);
                a[2] = (short)f2b(v0.z); a[3] = (short)f2b(v0.w);
                a[4] = (short)f2b(v1.x); a[5] = (short)f2b(v1.y);
                a[6] = (short)f2b(v1.z); a[7] = (short)f2b(v1.w);
                aF[i] = a;
            } else {
                aF[i] = *(const short8v*)((const unsigned short*)Av +
                                          (size_t)r * 128 + kb * 32 + l4 * 8);
            }
        }
        const int k8 = kb * 4 + l4;
#pragma unroll
        for (int j = 0; j < 8; ++j) {
            short8v bh = *(const short8v*)(WLh + (k8 * 128 + j * 16 + l15) * 8);
            short8v bl = *(const short8v*)(WLl + (k8 * 128 + j * 16 + l15) * 8);
            acc[0][j] = __builtin_amdgcn_mfma_f32_16x16x32_bf16(aF[0], bh, acc[0][j], 0, 0, 0);
            acc[1][j] = __builtin_amdgcn_mfma_f32_16x16x32_bf16(aF[1], bh, acc[1][j], 0, 0, 0);
            acc[0][j] = __builtin_amdgcn_mfma_f32_16x16x32_bf16(aF[0], bl, acc[0][j], 0, 0, 0);
            acc[1][j] = __builtin_amdgcn_mfma_f32_16x16x32_bf16(aF[1], bl, acc[1][j], 0, 0, 0);
        }
    }

    // C/D layout (m89-verified): col = lane&15, row = (lane>>4)*4 + reg. Scale rows by dinv.
#pragma unroll
    for (int i = 0; i < 2; ++i)
#pragma unroll
        for (int r = 0; r < 4; ++r) {
            int rr = m0 + i * 16 + l4 * 4 + r;
            if (rr < n) {
                float dvr = dinv[rr];
#pragma unroll
                for (int j = 0; j < 8; ++j)
                    C[(size_t)rr * 128 + j * 16 + l15] = f2b(acc[i][j][r] * dvr);
            }
        }
}

// ---------------- pull aggregation: 4 nodes / 256-thr block, 16-deep unroll, no atomics ----------------
// Table rows are pre-scaled by dinv[src]; h = relu(dinv[i]*(sum ew*Ts[src] + Ts[i]) + b).
__global__ __launch_bounds__(256) void agg_kernel(const int* __restrict__ start,
                                                  const unsigned int* __restrict__ sedge,
                                                  const float* __restrict__ dinv,
                                                  const unsigned short* __restrict__ xw,
                                                  const float* __restrict__ bias,
                                                  unsigned short* __restrict__ h, int n) {
    const int i = blockIdx.x * 4 + (threadIdx.x >> 6);
    if (i >= n) return;
    const int t = threadIdx.x & 63;  // feature pair (2t, 2t+1)
    unsigned int u = *(const unsigned int*)(xw + (size_t)i * DD + 2 * t);
    float a0 = blo(u);  // self-loop: Ts[i] with weight 1
    float a1 = bhi(u);
    const int s = start[i], e = start[i + 1];
    int k = s;
    for (; k + 15 < e; k += 16) {
        unsigned int pe[16], uu[16];
        float nv[16];
#pragma unroll
        for (int j = 0; j < 16; ++j) pe[j] = sedge[k + j];
#pragma unroll
        for (int j = 0; j < 16; ++j) {
            nv[j] = __uint_as_float((pe[j] & 0xffffu) << 16);
            uu[j] = *(const unsigned int*)(xw + (size_t)(pe[j] >> 16) * DD + 2 * t);
        }
#pragma unroll
        for (int j = 0; j < 16; ++j) {
            a0 += nv[j] * blo(uu[j]);
            a1 += nv[j] * bhi(uu[j]);
        }
    }
    for (; k + 3 < e; k += 4) {
        unsigned int pe[4], uu[4];
        float nv[4];
#pragma unroll
        for (int j = 0; j < 4; ++j) pe[j] = sedge[k + j];
#pragma unroll
        for (int j = 0; j < 4; ++j) {
            nv[j] = __uint_as_float((pe[j] & 0xffffu) << 16);
            uu[j] = *(const unsigned int*)(xw + (size_t)(pe[j] >> 16) * DD + 2 * t);
        }
#pragma unroll
        for (int j = 0; j < 4; ++j) {
            a0 += nv[j] * blo(uu[j]);
            a1 += nv[j] * bhi(uu[j]);
        }
    }
    for (; k < e; ++k) {
        unsigned int pe = sedge[k];
        float nvv = __uint_as_float((pe & 0xffffu) << 16);
        unsigned int u2 = *(const unsigned int*)(xw + (size_t)(pe >> 16) * DD + 2 * t);
        a0 += nvv * blo(u2);
        a1 += nvv * bhi(u2);
    }
    const float dv = dinv[i];
    a0 = fmaxf(dv * a0 + bias[2 * t], 0.f);
    a1 = fmaxf(dv * a1 + bias[2 * t + 1], 0.f);
    *(unsigned int*)(h + (size_t)i * DD + 2 * t) =
        (unsigned int)f2b(a0) | ((unsigned int)f2b(a1) << 16);
}

// ---------------- readout ----------------
__global__ __launch_bounds__(64) void colsum_partial_kernel(const unsigned short* __restrict__ h,
                                                            float* __restrict__ partial, int n) {
    int t = threadIdx.x;
    float a0 = 0.f, a1 = 0.f;
    for (int r = blockIdx.x; r < n; r += gridDim.x) {
        unsigned int u = *(const unsigned int*)(h + (size_t)r * DD + 2 * t);
        a0 += blo(u); a1 += bhi(u);
    }
    partial[blockIdx.x * DD + 2 * t] = a0;
    partial[blockIdx.x * DD + 2 * t + 1] = a1;
}

__global__ void final_kernel(const float* __restrict__ partial, const float* __restrict__ Wm,
                             const float* __restrict__ bm, float* __restrict__ out, int n) {
    __shared__ float g[DD];
    int t = threadIdx.x;
    float acc = 0.f;
    for (int b = 0; b < 512; ++b) acc += partial[b * DD + t];
    g[t] = acc / (float)n;
    __syncthreads();
    if (t < 10) {
        float o = bm[t];
#pragma unroll
        for (int d = 0; d < DD; ++d) o += g[d] * Wm[d * 10 + t];
        out[t] = o;
    }
}

extern "C" void kernel_launch(void* const* d_in, const int* in_sizes, int n_in,
                              void* d_out, int out_size, void* d_ws, size_t ws_size,
                              hipStream_t stream) {
    const float* x  = (const float*)d_in[0];
    const int*   ei = (const int*)d_in[1];
    const float* ew = (const float*)d_in[2];
    const float* W1 = (const float*)d_in[3];
    const float* b1 = (const float*)d_in[4];
    const float* W2 = (const float*)d_in[5];
    const float* b2 = (const float*)d_in[6];
    const float* Wm = (const float*)d_in[7];
    const float* bm = (const float*)d_in[8];
    float* out = (float*)d_out;

    const int n = in_sizes[0] / DD;   // 50000
    const int E = in_sizes[2];        // 800000
    const int* row = ei;
    const int* col = ei + E;

    const int nb = (n + 255) >> 8;            // 196 buckets (n <= 65536)
    const int edgeChunks = (E + 2047) / 2048; // 391

    uint2* binned = (uint2*)d_ws;                            // E (8B records)
    unsigned int* sedge = (unsigned int*)(binned + E);       // E (4B records)
    float* dinv    = (float*)(sedge + E);                    // n
    int*   startA  = (int*)(dinv + n);                       // n+1
    float* partial = (float*)(startA + n + 1);               // 512*128
    int*   gcnt    = (int*)(partial + 512 * DD);             // nb
    int*   bbase   = gcnt + nb;                              // nb+1
    int*   bcur    = bbase + nb + 1;                         // nb
    uintptr_t p = (uintptr_t)(bcur + nb);
    p = (p + 15) & ~(uintptr_t)15;
    unsigned short* T0   = (unsigned short*)p;               // n*128 bf16 (scaled xw)
    unsigned short* T1   = T0 + (size_t)n * DD;              // n*128 bf16 (h)
    unsigned short* Wt1h = T1 + (size_t)n * DD;              // 16384 each
    unsigned short* Wt1l = Wt1h + 16384;
    unsigned short* Wt2h = Wt1l + 16384;
    unsigned short* Wt2l = Wt2h + 16384;

    // --- conversions (+ gcnt zero inside wconv2 block 0) ---
    wconv2_kernel<<<128, 256, 0, stream>>>(W1, Wt1h, Wt1l, W2, Wt2h, Wt2l, gcnt, nb);

    // --- bucketed CSR build ---
    bucket_hist_kernel<<<edgeChunks, 256, 0, stream>>>(col, gcnt, E, nb);
    bucket_scan_kernel<<<1, 256, 0, stream>>>(gcnt, bbase, bcur, nb);
    bin_kernel<<<edgeChunks, 256, 0, stream>>>(row, col, ew, bcur, binned, E);
    build_csr_kernel<<<nb, 256, 0, stream>>>(binned, bbase, startA, dinv, sedge, n);

    const int gemmBlocks = (n + 127) / 128;  // 391
    const int aggBlocks = (n + 3) / 4;       // 12500

    // --- layer 1 (fp32 A path: xconv fused into GEMM) ---
    mfma_gemm_kernel<true><<<gemmBlocks, 256, 0, stream>>>(x, Wt1h, Wt1l, dinv, T0, n);
    agg_kernel<<<aggBlocks, 256, 0, stream>>>(startA, sedge, dinv, T0, b1, T1, n);

    // --- layer 2 ---
    mfma_gemm_kernel<false><<<gemmBlocks, 256, 0, stream>>>(T1, Wt2h, Wt2l, dinv, T0, n);
    agg_kernel<<<aggBlocks, 256, 0, stream>>>(startA, sedge, dinv, T0, b2, T1, n);

    // --- readout ---
    colsum_partial_kernel<<<512, 64, 0, stream>>>(T1, partial, n);
    final_kernel<<<1, 128, 0, stream>>>(partial, Wm, bm, out, n);
}